// Round 2
// baseline (128.792 us; speedup 1.0000x reference)
//
#include <hip/hip_runtime.h>
#include <stdint.h>
#include <math.h>

#define BSZ 4096
#define DIM 768
#define TEMP 0.07f

typedef short short8 __attribute__((ext_vector_type(8)));
typedef float f32x4 __attribute__((ext_vector_type(4)));

// ---------- helpers ----------

__device__ __forceinline__ uint16_t f2bf(float f) {
  uint32_t u = __float_as_uint(f);
  uint32_t r = (u + 0x7FFFu + ((u >> 16) & 1u)) >> 16;  // RNE
  return (uint16_t)r;
}

__device__ __forceinline__ void gll16(const void* g, void* l) {
  __builtin_amdgcn_global_load_lds(
      (__attribute__((address_space(1))) void*)(uintptr_t)g,
      (__attribute__((address_space(3))) void*)l,
      16, 0, 0);
}

// sorted-desc top-5 insert
__device__ __forceinline__ void ins5(float v, float& a, float& b, float& c,
                                     float& d, float& e) {
  if (v > e) {
    e = v;
    if (e > d) { float t = d; d = e; e = t;
      if (d > c) { t = c; c = d; d = t;
        if (c > b) { t = b; b = c; c = t;
          if (b > a) { t = a; a = b; b = t; } } } }
  }
}

// ---------- K1: normalize + cast to bf16 ----------
__global__ __launch_bounds__(256) void k_norm(const float* __restrict__ text,
                                              const float* __restrict__ table,
                                              uint16_t* __restrict__ tn,
                                              uint16_t* __restrict__ zn) {
  int row = blockIdx.x & (BSZ - 1);
  bool isTable = blockIdx.x >= BSZ;
  const float* src = (isTable ? table : text) + (size_t)row * DIM;
  uint16_t* dst = (isTable ? zn : tn) + (size_t)row * DIM;
  int tid = threadIdx.x;

  float x0 = src[tid];
  float x1 = src[tid + 256];
  float x2 = src[tid + 512];
  float ss = x0 * x0 + x1 * x1 + x2 * x2;
  #pragma unroll
  for (int off = 32; off >= 1; off >>= 1) ss += __shfl_xor(ss, off);
  __shared__ float wss[4];
  if ((tid & 63) == 0) wss[tid >> 6] = ss;
  __syncthreads();
  float inv = rsqrtf(wss[0] + wss[1] + wss[2] + wss[3]);
  dst[tid]       = f2bf(x0 * inv);
  dst[tid + 256] = f2bf(x1 * inv);
  dst[tid + 512] = f2bf(x2 * inv);
}

// ---------- K2: sim = Zn @ Tn^T  (256x256 tile, BK=64, counted-vmcnt pipeline)
// + FUSED row/col top-5 partials in the epilogue (k_tile eliminated).
// 512 threads = 8 waves (2M x 4N), wave tile 128x64.
// Grid 256 blocks, XCD-swizzled: each XCD owns a 4x8 region of the 16x16 grid
// (working set 4 A-panels + 8 B-panels = 4.5 MB ~ L2).
__global__ __launch_bounds__(512, 2) void k_gemm(const uint16_t* __restrict__ Zb,
                                                 const uint16_t* __restrict__ Tb,
                                                 float* __restrict__ sim,
                                                 float* __restrict__ rp,
                                                 float* __restrict__ cp) {
  extern __shared__ __attribute__((aligned(16))) char lds[];

  int tid = threadIdx.x;
  int wave = tid >> 6, lane = tid & 63;
  int wm = wave >> 2, wn = wave & 3;

  // XCD-aware swizzle: xcd = bid%8 gets a 4(brow) x 8(bcol) contiguous region.
  int bid = blockIdx.x;
  int xcd = bid & 7, li = bid >> 3;
  int brow = (((xcd >> 1) << 2) + (li >> 3)) << 8;
  int bcol = (((xcd & 1) << 3) + (li & 7)) << 8;

  f32x4 acc[8][4] = {};

  const uint16_t* gA = Zb + (size_t)brow * DIM + wave * 8;
  const uint16_t* gB = Tb + (size_t)bcol * DIM + wave * 8;
  char* ldsA = lds + (wave << 12);  // this wave's kc slab

  int kqg = lane >> 4;                          // 0..3
  int rbyte = ((wm << 7) + (lane & 15)) << 4;   // A row base byte within kc-slab
  int cbyte = ((wn << 6) + (lane & 15)) << 4;   // B row base byte

  auto SA = [&](int t2, int bb, int rg) {
    gll16(gA + (size_t)t2 * 64 + (size_t)(rg * 64 + lane) * DIM,
          ldsA + bb + rg * 1024);
  };
  auto SB = [&](int t2, int bb, int rg) {
    gll16(gB + (size_t)t2 * 64 + (size_t)(rg * 64 + lane) * DIM,
          ldsA + bb + 32768 + rg * 1024);
  };

  auto LOADB = [&](int bb, short8 (&bf)[2][4]) {
    #pragma unroll
    for (int ks = 0; ks < 2; ++ks) {
      const char* Bb = lds + bb + (((ks << 2) + kqg) << 12) + 32768;
      #pragma unroll
      for (int n = 0; n < 4; ++n)
        bf[ks][n] = *(const short8*)(Bb + cbyte + (n << 8));
    }
  };
  auto PHASE = [&](int bb, int mlo, short8 (&bf)[2][4]) {
    __builtin_amdgcn_s_setprio(1);
    #pragma unroll
    for (int ks = 0; ks < 2; ++ks) {
      const char* Ab = lds + bb + (((ks << 2) + kqg) << 12);
      #pragma unroll
      for (int m = 0; m < 4; ++m) {
        short8 af = *(const short8*)(Ab + rbyte + ((mlo + m) << 8));
        #pragma unroll
        for (int n = 0; n < 4; ++n)
          acc[mlo + m][n] = __builtin_amdgcn_mfma_f32_16x16x32_bf16(
              af, bf[ks][n], acc[mlo + m][n], 0, 0, 0);
      }
    }
    __builtin_amdgcn_s_setprio(0);
  };

  // ---- prologue: stage tiles 0 and 1; land tile 0, keep 1 in flight
  #pragma unroll
  for (int rg = 0; rg < 4; ++rg) { SA(0, 0, rg); SB(0, 0, rg); }
  #pragma unroll
  for (int rg = 0; rg < 4; ++rg) { SA(1, 65536, rg); SB(1, 65536, rg); }
  asm volatile("s_waitcnt vmcnt(8)" ::: "memory");
  __builtin_amdgcn_s_barrier();

  // ---- main loop: tiles 0..9, staging tiles 2..11
  #pragma unroll 2
  for (int t = 0; t < 10; ++t) {
    int bb = (t & 1) << 16;
    short8 bf[2][4];
    LOADB(bb, bf);
    PHASE(bb, 0, bf);
    __builtin_amdgcn_s_barrier();
    SA(t + 2, bb, 0); SA(t + 2, bb, 2);
    SB(t + 2, bb, 0); SB(t + 2, bb, 1); SB(t + 2, bb, 2); SB(t + 2, bb, 3);
    PHASE(bb, 4, bf);
    __builtin_amdgcn_s_barrier();
    SA(t + 2, bb, 1); SA(t + 2, bb, 3);
    asm volatile("s_waitcnt vmcnt(8)" ::: "memory");  // retire tile t+1's loads only
    __builtin_amdgcn_s_barrier();
  }

  // ---- epilogue tiles: 10 (buf0), 11 (buf1)
  {
    short8 bf[2][4];
    LOADB(0, bf);
    PHASE(0, 0, bf);
    PHASE(0, 4, bf);
  }
  asm volatile("s_waitcnt vmcnt(0)" ::: "memory");
  __builtin_amdgcn_s_barrier();
  {
    short8 bf[2][4];
    LOADB(65536, bf);
    PHASE(65536, 0, bf);
    PHASE(65536, 4, bf);
  }

  // ---- store sim (true values incl. diagonal); C/D: col=lane&15, row=(lane>>4)*4+r
  int crow0 = brow + (wm << 7) + ((lane >> 4) << 2);
  int ccol0 = bcol + (wn << 6) + (lane & 15);
  #pragma unroll
  for (int m = 0; m < 8; ++m)
    #pragma unroll
    for (int n = 0; n < 4; ++n)
      #pragma unroll
      for (int r = 0; r < 4; ++r)
        sim[(size_t)(crow0 + m * 16 + r) * BSZ + (ccol0 + n * 16)] = acc[m][n][r];

  // ---- fused top-5: two 128-row passes through LDS (f32 [128][256], chunk^row&7)
  float* l32 = (float*)lds;
  const bool diagblk = (brow == bcol);
  int rtile = brow >> 8, ctile = bcol >> 8;

  #pragma unroll 1
  for (int p = 0; p < 2; ++p) {
    __syncthreads();  // prior LDS readers done
    if (wm == p) {
      #pragma unroll
      for (int m = 0; m < 8; ++m) {
        int lrb = (m << 4) + ((lane >> 4) << 2);
        #pragma unroll
        for (int n = 0; n < 4; ++n) {
          int lc = (wn << 6) + (n << 4) + (lane & 15);
          #pragma unroll
          for (int r = 0; r < 4; ++r) {
            int row = lrb + r;
            float v = acc[m][n][r];
            if (diagblk && lc == (p << 7) + row) v = -1e30f;  // mask diag in LDS only
            l32[(row << 8) + ((((lc >> 2) ^ (row & 7)) << 2) | (lc & 3))] = v;
          }
        }
      }
    }
    __syncthreads();

    // row scan: 4 threads/row, 64 cols each via 16 x b128
    {
      int r4 = tid >> 2, qt = tid & 3;
      const float* rowbase = l32 + (r4 << 8);
      int rx = r4 & 7;
      float a0 = -1e30f, a1 = -1e30f, a2 = -1e30f, a3 = -1e30f, a4 = -1e30f;
      #pragma unroll
      for (int k = 0; k < 16; ++k) {
        int c16 = (qt << 4) + k;
        f32x4 v = *(const f32x4*)(rowbase + ((c16 ^ rx) << 2));
        ins5(v[0], a0, a1, a2, a3, a4);
        ins5(v[1], a0, a1, a2, a3, a4);
        ins5(v[2], a0, a1, a2, a3, a4);
        ins5(v[3], a0, a1, a2, a3, a4);
      }
      #pragma unroll
      for (int xr = 1; xr <= 2; xr <<= 1) {
        float b0 = __shfl_xor(a0, xr), b1 = __shfl_xor(a1, xr),
              b2 = __shfl_xor(a2, xr), b3 = __shfl_xor(a3, xr),
              b4 = __shfl_xor(a4, xr);
        ins5(b0, a0, a1, a2, a3, a4);
        ins5(b1, a0, a1, a2, a3, a4);
        ins5(b2, a0, a1, a2, a3, a4);
        ins5(b3, a0, a1, a2, a3, a4);
        ins5(b4, a0, a1, a2, a3, a4);
      }
      if (qt == 0) {
        float* pr = rp + ((size_t)(brow + (p << 7) + r4) * 16 + ctile) * 5;
        pr[0] = a0; pr[1] = a1; pr[2] = a2; pr[3] = a3; pr[4] = a4;
      }
    }

    // col scan: 2 threads/col, 64 rows each via b32
    {
      int c2 = tid >> 1, hf = tid & 1;
      int cchunk = c2 >> 2, cw = c2 & 3;
      float a0 = -1e30f, a1 = -1e30f, a2 = -1e30f, a3 = -1e30f, a4 = -1e30f;
      #pragma unroll 8
      for (int k = 0; k < 64; ++k) {
        int rr = (hf << 6) + k;
        float v = l32[(rr << 8) + (((cchunk ^ (rr & 7)) << 2) | cw)];
        ins5(v, a0, a1, a2, a3, a4);
      }
      float b0 = __shfl_xor(a0, 1), b1 = __shfl_xor(a1, 1),
            b2 = __shfl_xor(a2, 1), b3 = __shfl_xor(a3, 1),
            b4 = __shfl_xor(a4, 1);
      ins5(b0, a0, a1, a2, a3, a4);
      ins5(b1, a0, a1, a2, a3, a4);
      ins5(b2, a0, a1, a2, a3, a4);
      ins5(b3, a0, a1, a2, a3, a4);
      ins5(b4, a0, a1, a2, a3, a4);
      if (hf == 0) {
        float* pc = cp + ((size_t)(bcol + c2) * 16 + rtile) * 5;
        pc[0] = a0; pc[1] = a1; pc[2] = a2; pc[3] = a3; pc[4] = a4;
      }
    }
  }
}

// ---------- K4: merge partials (wave per line) + loss ----------
__global__ __launch_bounds__(256) void k_merge(const float* __restrict__ sim,
                                               const float* __restrict__ rp,
                                               const float* __restrict__ cp,
                                               float* __restrict__ lossbuf) {
  int wave = threadIdx.x >> 6, lane = threadIdx.x & 63;
  int wid = blockIdx.x * 4 + wave;
  bool isCol = wid >= BSZ;
  int line = isCol ? wid - BSZ : wid;
  const float* src = (isCol ? cp : rp) + (size_t)line * 80;

  float t0 = -1e30f, t1 = -1e30f, t2 = -1e30f, t3 = -1e30f, t4 = -1e30f;
  ins5(src[lane], t0, t1, t2, t3, t4);
  if (lane < 16) ins5(src[lane + 64], t0, t1, t2, t3, t4);

  float top[5];
  #pragma unroll
  for (int e = 0; e < 5; e++) {
    float m = t0;
    #pragma unroll
    for (int off = 32; off >= 1; off >>= 1) m = fmaxf(m, __shfl_xor(m, off));
    unsigned long long msk = __ballot(t0 == m);
    int owner = __ffsll(msk) - 1;
    if (lane == owner) { t0 = t1; t1 = t2; t2 = t3; t3 = t4; t4 = -1e30f; }
    top[e] = m;
  }

  if (lane == 0) {
    float pos = sim[(size_t)line * BSZ + line] / TEMP;
    float l0 = top[0] / TEMP, l1 = top[1] / TEMP, l2 = top[2] / TEMP,
          l3 = top[3] / TEMP, l4 = top[4] / TEMP;
    float mx = fmaxf(pos, fmaxf(fmaxf(l0, l1), fmaxf(fmaxf(l2, l3), l4)));
    float s = expf(pos - mx) + expf(l0 - mx) + expf(l1 - mx) +
              expf(l2 - mx) + expf(l3 - mx) + expf(l4 - mx);
    lossbuf[wid] = mx + logf(s) - pos;
  }
}

// ---------- K5: final reduction ----------
__global__ __launch_bounds__(256) void k_reduce(const float* __restrict__ losses,
                                                float* __restrict__ out) {
  int tid = threadIdx.x;
  float s = 0.f;
  for (int i = tid; i < 2 * BSZ; i += 256) s += losses[i];
  #pragma unroll
  for (int off = 32; off >= 1; off >>= 1) s += __shfl_xor(s, off);
  __shared__ float wss[4];
  if ((tid & 63) == 0) wss[tid >> 6] = s;
  __syncthreads();
  if (tid == 0) out[0] = (wss[0] + wss[1] + wss[2] + wss[3]) / (2.0f * BSZ);
}

// ---------- launcher ----------
extern "C" void kernel_launch(void* const* d_in, const int* in_sizes, int n_in,
                              void* d_out, int out_size, void* d_ws, size_t ws_size,
                              hipStream_t stream) {
  const float* text = (const float*)d_in[0];
  const float* table = (const float*)d_in[1];
  float* out = (float*)d_out;
  float* sim = out + 1;  // d_out = [loss, sim(4096x4096)]

  uint16_t* Zb = (uint16_t*)d_ws;
  uint16_t* Tb = Zb + (size_t)BSZ * DIM;
  float* lossbuf = (float*)(Tb + (size_t)BSZ * DIM);  // 2*BSZ floats
  // rp/cp no longer alias Zb/Tb (k_gemm writes them while reading Zb/Tb).
  // ws usage: 12.6 MB (Zb+Tb) + 32 KB + 2*1.31 MB ≈ 15.3 MB.
  float* rp = lossbuf + 2 * BSZ;             // [4096][16][5]
  float* cp = rp + (size_t)BSZ * 16 * 5;     // [4096][16][5]

  k_norm<<<2 * BSZ, 256, 0, stream>>>(text, table, Tb, Zb);
  k_gemm<<<(BSZ / 256) * (BSZ / 256), 512, 131072, stream>>>(Zb, Tb, sim, rp, cp);
  k_merge<<<2 * BSZ / 4, 256, 0, stream>>>(sim, rp, cp, lossbuf);
  k_reduce<<<1, 256, 0, stream>>>(lossbuf, out);
}

// Round 3
// 89.168 us; speedup vs baseline: 1.4444x; 1.4444x over previous
//
#include <hip/hip_runtime.h>
#include <stdint.h>
#include <math.h>

#define BSZ 4096
#define DIM 768
#define TEMP 0.07f

typedef short short8 __attribute__((ext_vector_type(8)));
typedef float f32x4 __attribute__((ext_vector_type(4)));

// ---------- helpers ----------

__device__ __forceinline__ uint16_t f2bf(float f) {
  uint32_t u = __float_as_uint(f);
  uint32_t r = (u + 0x7FFFu + ((u >> 16) & 1u)) >> 16;  // RNE
  return (uint16_t)r;
}

__device__ __forceinline__ void gll16(const void* g, void* l) {
  __builtin_amdgcn_global_load_lds(
      (__attribute__((address_space(1))) void*)(uintptr_t)g,
      (__attribute__((address_space(3))) void*)l,
      16, 0, 0);
}

// branchy sorted-desc top-5 insert (kept for tiny k_merge only)
__device__ __forceinline__ void ins5(float v, float& a, float& b, float& c,
                                     float& d, float& e) {
  if (v > e) {
    e = v;
    if (e > d) { float t = d; d = e; e = t;
      if (d > c) { t = c; c = d; d = t;
        if (c > b) { t = b; b = c; c = t;
          if (b > a) { t = a; a = b; b = t; } } } }
  }
}

// branchless sorted-desc top-5 insert: 9 v_min/v_max, no divergence
__device__ __forceinline__ void sins5(float v, float& a, float& b, float& c,
                                      float& d, float& e) {
  float t;
  t = fmaxf(a, v); v = fminf(a, v); a = t;
  t = fmaxf(b, v); v = fminf(b, v); b = t;
  t = fmaxf(c, v); v = fminf(c, v); c = t;
  t = fmaxf(d, v); v = fminf(d, v); d = t;
  e = fmaxf(e, v);
}

// ---------- K1: normalize + cast to bf16 ----------
__global__ __launch_bounds__(256) void k_norm(const float* __restrict__ text,
                                              const float* __restrict__ table,
                                              uint16_t* __restrict__ tn,
                                              uint16_t* __restrict__ zn) {
  int row = blockIdx.x & (BSZ - 1);
  bool isTable = blockIdx.x >= BSZ;
  const float* src = (isTable ? table : text) + (size_t)row * DIM;
  uint16_t* dst = (isTable ? zn : tn) + (size_t)row * DIM;
  int tid = threadIdx.x;

  float x0 = src[tid];
  float x1 = src[tid + 256];
  float x2 = src[tid + 512];
  float ss = x0 * x0 + x1 * x1 + x2 * x2;
  #pragma unroll
  for (int off = 32; off >= 1; off >>= 1) ss += __shfl_xor(ss, off);
  __shared__ float wss[4];
  if ((tid & 63) == 0) wss[tid >> 6] = ss;
  __syncthreads();
  float inv = rsqrtf(wss[0] + wss[1] + wss[2] + wss[3]);
  dst[tid]       = f2bf(x0 * inv);
  dst[tid + 256] = f2bf(x1 * inv);
  dst[tid + 512] = f2bf(x2 * inv);
}

// ---------- K2: sim = Zn @ Tn^T  (256x256 tile, BK=64, counted-vmcnt pipeline)
// (round-1 version, verbatim — 50 us, VGPR 100)
__global__ __launch_bounds__(512, 2) void k_gemm(const uint16_t* __restrict__ Zb,
                                                 const uint16_t* __restrict__ Tb,
                                                 float* __restrict__ sim) {
  extern __shared__ __attribute__((aligned(16))) char lds[];

  int tid = threadIdx.x;
  int wave = tid >> 6, lane = tid & 63;
  int wm = wave >> 2, wn = wave & 3;
  int brow = (blockIdx.x >> 4) << 8;
  int bcol = (blockIdx.x & 15) << 8;

  f32x4 acc[8][4] = {};

  const uint16_t* gA = Zb + (size_t)brow * DIM + wave * 8;
  const uint16_t* gB = Tb + (size_t)bcol * DIM + wave * 8;
  char* ldsA = lds + (wave << 12);  // this wave's kc slab

  int kqg = lane >> 4;                          // 0..3
  int rbyte = ((wm << 7) + (lane & 15)) << 4;   // A row base byte within kc-slab
  int cbyte = ((wn << 6) + (lane & 15)) << 4;   // B row base byte

  auto SA = [&](int t2, int bb, int rg) {
    gll16(gA + (size_t)t2 * 64 + (size_t)(rg * 64 + lane) * DIM,
          ldsA + bb + rg * 1024);
  };
  auto SB = [&](int t2, int bb, int rg) {
    gll16(gB + (size_t)t2 * 64 + (size_t)(rg * 64 + lane) * DIM,
          ldsA + bb + 32768 + rg * 1024);
  };

  auto LOADB = [&](int bb, short8 (&bf)[2][4]) {
    #pragma unroll
    for (int ks = 0; ks < 2; ++ks) {
      const char* Bb = lds + bb + (((ks << 2) + kqg) << 12) + 32768;
      #pragma unroll
      for (int n = 0; n < 4; ++n)
        bf[ks][n] = *(const short8*)(Bb + cbyte + (n << 8));
    }
  };
  auto PHASE = [&](int bb, int mlo, short8 (&bf)[2][4]) {
    __builtin_amdgcn_s_setprio(1);
    #pragma unroll
    for (int ks = 0; ks < 2; ++ks) {
      const char* Ab = lds + bb + (((ks << 2) + kqg) << 12);
      #pragma unroll
      for (int m = 0; m < 4; ++m) {
        short8 af = *(const short8*)(Ab + rbyte + ((mlo + m) << 8));
        #pragma unroll
        for (int n = 0; n < 4; ++n)
          acc[mlo + m][n] = __builtin_amdgcn_mfma_f32_16x16x32_bf16(
              af, bf[ks][n], acc[mlo + m][n], 0, 0, 0);
      }
    }
    __builtin_amdgcn_s_setprio(0);
  };

  // ---- prologue: stage tiles 0 and 1 (16 loads); land tile 0, keep 1 in flight
  #pragma unroll
  for (int rg = 0; rg < 4; ++rg) { SA(0, 0, rg); SB(0, 0, rg); }
  #pragma unroll
  for (int rg = 0; rg < 4; ++rg) { SA(1, 65536, rg); SB(1, 65536, rg); }
  asm volatile("s_waitcnt vmcnt(8)" ::: "memory");
  __builtin_amdgcn_s_barrier();

  // ---- main loop: tiles 0..9, staging tiles 2..11
  #pragma unroll 2
  for (int t = 0; t < 10; ++t) {
    int bb = (t & 1) << 16;
    short8 bf[2][4];
    LOADB(bb, bf);
    PHASE(bb, 0, bf);
    __builtin_amdgcn_s_barrier();
    SA(t + 2, bb, 0); SA(t + 2, bb, 2);
    SB(t + 2, bb, 0); SB(t + 2, bb, 1); SB(t + 2, bb, 2); SB(t + 2, bb, 3);
    PHASE(bb, 4, bf);
    __builtin_amdgcn_s_barrier();
    SA(t + 2, bb, 1); SA(t + 2, bb, 3);
    asm volatile("s_waitcnt vmcnt(8)" ::: "memory");  // retire tile t+1's loads only
    __builtin_amdgcn_s_barrier();
  }

  // ---- epilogue tiles: 10 (buf0), 11 (buf1) — no further staging
  {
    short8 bf[2][4];
    LOADB(0, bf);
    PHASE(0, 0, bf);
    PHASE(0, 4, bf);
  }
  asm volatile("s_waitcnt vmcnt(0)" ::: "memory");
  __builtin_amdgcn_s_barrier();
  {
    short8 bf[2][4];
    LOADB(65536, bf);
    PHASE(65536, 0, bf);
    PHASE(65536, 4, bf);
  }

  // epilogue: C/D layout col=lane&15, row=(lane>>4)*4+reg
  int crow0 = brow + (wm << 7) + ((lane >> 4) << 2);
  int ccol0 = bcol + (wn << 6) + (lane & 15);
  #pragma unroll
  for (int m = 0; m < 8; ++m)
    #pragma unroll
    for (int n = 0; n < 4; ++n)
      #pragma unroll
      for (int r = 0; r < 4; ++r)
        sim[(size_t)(crow0 + m * 16 + r) * BSZ + (ccol0 + n * 16)] = acc[m][n][r];
}

// ---------- K3: tile pass — row & col partial top-5 (branchless, b128, 1 barrier)
// 1024 blocks, 256 threads, 128x128 tile in 64 KiB LDS.
// LDS layout: l32[row*128 + ((chunk ^ (row&7))<<2) + w]  (chunk = col>>2, w = col&3)
//  -> row b128 reads conflict-free, col b32 reads 2-way (free).
__global__ __launch_bounds__(256) void k_tile(const float* __restrict__ sim,
                                              float* __restrict__ rp,
                                              float* __restrict__ cp) {
  extern __shared__ float l32[];  // 128*128 floats = 64 KiB
  int tid = threadIdx.x;
  int tr = blockIdx.x >> 5, tc = blockIdx.x & 31;
  int row0 = tr << 7, col0 = tc << 7;
  bool diag = (tr == tc);

  // ---- stage: 16 x f32x4 coalesced loads (2 rows x 512B per wave per step)
  int q = tid & 31;   // chunk col 0..31
  int g = tid >> 5;   // row group 0..7 (rows g*16 .. g*16+15)
  const float* gsrc = sim + (size_t)(row0 + (g << 4)) * BSZ + col0 + (q << 2);

  f32x4 v[16];
  #pragma unroll
  for (int k = 0; k < 16; ++k)
    v[k] = *(const f32x4*)(gsrc + (size_t)k * BSZ);

  #pragma unroll
  for (int k = 0; k < 16; ++k) {
    int r = (g << 4) + k;
    if (diag && (r >> 2) == q) v[k][r & 3] = -1e30f;  // mask diagonal
    *(f32x4*)(l32 + (r << 7) + ((q ^ (r & 7)) << 2)) = v[k];
  }
  __syncthreads();

  // ---- row scan: 2 threads/row, 64 cols each via 16 x b128
  {
    int row = tid >> 1, h = tid & 1;
    int rx = row & 7;
    const float* rb = l32 + (row << 7);
    float a0 = -1e30f, a1 = -1e30f, a2 = -1e30f, a3 = -1e30f, a4 = -1e30f;
    #pragma unroll
    for (int j = 0; j < 16; ++j) {
      int c16 = (h << 4) + j;
      f32x4 x = *(const f32x4*)(rb + ((c16 ^ rx) << 2));
      sins5(x[0], a0, a1, a2, a3, a4);
      sins5(x[1], a0, a1, a2, a3, a4);
      sins5(x[2], a0, a1, a2, a3, a4);
      sins5(x[3], a0, a1, a2, a3, a4);
    }
    float b0 = __shfl_xor(a0, 1), b1 = __shfl_xor(a1, 1),
          b2 = __shfl_xor(a2, 1), b3 = __shfl_xor(a3, 1),
          b4 = __shfl_xor(a4, 1);
    sins5(b0, a0, a1, a2, a3, a4);
    sins5(b1, a0, a1, a2, a3, a4);
    sins5(b2, a0, a1, a2, a3, a4);
    sins5(b3, a0, a1, a2, a3, a4);
    sins5(b4, a0, a1, a2, a3, a4);
    if (h == 0) {
      float* pr = rp + ((size_t)(row0 + row) * 32 + tc) * 5;
      pr[0] = a0; pr[1] = a1; pr[2] = a2; pr[3] = a3; pr[4] = a4;
    }
  }

  // ---- col scan: 2 threads/col, 64 rows each via b32 (no barrier needed: read-only)
  {
    int c = tid >> 1, hf = tid & 1;
    int cc = c >> 2, cw = c & 3;
    float a0 = -1e30f, a1 = -1e30f, a2 = -1e30f, a3 = -1e30f, a4 = -1e30f;
    #pragma unroll 8
    for (int k = 0; k < 64; ++k) {
      int r = (hf << 6) + k;
      float x = l32[(r << 7) + (((cc ^ (r & 7)) << 2) | cw)];
      sins5(x, a0, a1, a2, a3, a4);
    }
    float b0 = __shfl_xor(a0, 1), b1 = __shfl_xor(a1, 1),
          b2 = __shfl_xor(a2, 1), b3 = __shfl_xor(a3, 1),
          b4 = __shfl_xor(a4, 1);
    sins5(b0, a0, a1, a2, a3, a4);
    sins5(b1, a0, a1, a2, a3, a4);
    sins5(b2, a0, a1, a2, a3, a4);
    sins5(b3, a0, a1, a2, a3, a4);
    sins5(b4, a0, a1, a2, a3, a4);
    if (hf == 0) {
      float* pc = cp + ((size_t)(col0 + c) * 32 + tr) * 5;
      pc[0] = a0; pc[1] = a1; pc[2] = a2; pc[3] = a3; pc[4] = a4;
    }
  }
}

// ---------- K4: merge partials (wave per line) + loss ----------
__global__ __launch_bounds__(256) void k_merge(const float* __restrict__ sim,
                                               const float* __restrict__ rp,
                                               const float* __restrict__ cp,
                                               float* __restrict__ lossbuf) {
  int wave = threadIdx.x >> 6, lane = threadIdx.x & 63;
  int wid = blockIdx.x * 4 + wave;
  bool isCol = wid >= BSZ;
  int line = isCol ? wid - BSZ : wid;
  const float* src = (isCol ? cp : rp) + (size_t)line * 160;

  float t0 = -1e30f, t1 = -1e30f, t2 = -1e30f, t3 = -1e30f, t4 = -1e30f;
  ins5(src[lane], t0, t1, t2, t3, t4);
  ins5(src[lane + 64], t0, t1, t2, t3, t4);
  if (lane < 32) ins5(src[lane + 128], t0, t1, t2, t3, t4);

  float top[5];
  #pragma unroll
  for (int e = 0; e < 5; e++) {
    float m = t0;
    #pragma unroll
    for (int off = 32; off >= 1; off >>= 1) m = fmaxf(m, __shfl_xor(m, off));
    unsigned long long msk = __ballot(t0 == m);
    int owner = __ffsll(msk) - 1;
    if (lane == owner) { t0 = t1; t1 = t2; t2 = t3; t3 = t4; t4 = -1e30f; }
    top[e] = m;
  }

  if (lane == 0) {
    float pos = sim[(size_t)line * BSZ + line] / TEMP;
    float l0 = top[0] / TEMP, l1 = top[1] / TEMP, l2 = top[2] / TEMP,
          l3 = top[3] / TEMP, l4 = top[4] / TEMP;
    float mx = fmaxf(pos, fmaxf(fmaxf(l0, l1), fmaxf(fmaxf(l2, l3), l4)));
    float s = expf(pos - mx) + expf(l0 - mx) + expf(l1 - mx) +
              expf(l2 - mx) + expf(l3 - mx) + expf(l4 - mx);
    lossbuf[wid] = mx + logf(s) - pos;
  }
}

// ---------- K5: final reduction ----------
__global__ __launch_bounds__(256) void k_reduce(const float* __restrict__ losses,
                                                float* __restrict__ out) {
  int tid = threadIdx.x;
  float s = 0.f;
  for (int i = tid; i < 2 * BSZ; i += 256) s += losses[i];
  #pragma unroll
  for (int off = 32; off >= 1; off >>= 1) s += __shfl_xor(s, off);
  __shared__ float wss[4];
  if ((tid & 63) == 0) wss[tid >> 6] = s;
  __syncthreads();
  if (tid == 0) out[0] = (wss[0] + wss[1] + wss[2] + wss[3]) / (2.0f * BSZ);
}

// ---------- launcher ----------
extern "C" void kernel_launch(void* const* d_in, const int* in_sizes, int n_in,
                              void* d_out, int out_size, void* d_ws, size_t ws_size,
                              hipStream_t stream) {
  const float* text = (const float*)d_in[0];
  const float* table = (const float*)d_in[1];
  float* out = (float*)d_out;
  float* sim = out + 1;  // d_out = [loss, sim(4096x4096)]

  uint16_t* Zb = (uint16_t*)d_ws;
  uint16_t* Tb = Zb + (size_t)BSZ * DIM;
  float* lossbuf = (float*)(Tb + (size_t)BSZ * DIM);  // 2*BSZ floats

  // rp/cp alias the Zb/Tb region (dead after k_gemm; stream-ordered).
  float* rp = (float*)d_ws;                  // [4096][32][5]
  float* cp = rp + (size_t)BSZ * 32 * 5;     // [4096][32][5]

  k_norm<<<2 * BSZ, 256, 0, stream>>>(text, table, Tb, Zb);
  k_gemm<<<(BSZ / 256) * (BSZ / 256), 512, 131072, stream>>>(Zb, Tb, sim);
  k_tile<<<32 * 32, 256, 65536, stream>>>(sim, rp, cp);
  k_merge<<<2 * BSZ / 4, 256, 0, stream>>>(sim, rp, cp, lossbuf);
  k_reduce<<<1, 256, 0, stream>>>(lossbuf, out);
}